// Round 1
// baseline (277.169 us; speedup 1.0000x reference)
//
#include <hip/hip_runtime.h>
#include <hip/hip_bf16.h>

#define HW 3136
#define NB 16

typedef float f32x4 __attribute__((ext_vector_type(4)));
typedef short short8 __attribute__((ext_vector_type(8)));

__device__ inline unsigned short bfb(float f) {
  union { __hip_bfloat16 h; unsigned short u; } cv;
  cv.h = __float2bfloat16(f);
  return cv.u;
}
__device__ inline unsigned pack2(float lo, float hi) {
  return (unsigned)bfb(lo) | ((unsigned)bfb(hi) << 16);
}
// order-preserving float<->uint encode for atomicMax
__device__ inline unsigned fenc(float f) {
  unsigned u = __float_as_uint(f);
  return (u & 0x80000000u) ? ~u : (u | 0x80000000u);
}
__device__ inline float fdec(unsigned e) {
  return (e & 0x80000000u) ? __uint_as_float(e & 0x7FFFFFFFu) : __uint_as_float(~e);
}

// ---------------- K0: convert W to bf16, zero pool buffers ----------------
__global__ __launch_bounds__(256) void k0_init(const float* __restrict__ conv_w,
                                               unsigned short* __restrict__ Wbf,
                                               float* __restrict__ psum,
                                               unsigned* __restrict__ pmaxe) {
  int i = blockIdx.x * 256 + threadIdx.x;
  Wbf[i] = bfb(conv_w[i]);                // 65536 threads, one each
  if (i < 4096) psum[i] = 0.f;
  else if (i < 8192) pmaxe[i - 4096] = 0u; // fdec(0) = -NaN, below all reals
}

// ---------------- K1: conv1x1 + bias + GELU -> h ; fused channel pooling ----------------
__global__ __launch_bounds__(256) void k1_conv_gelu_pool(
    const float* __restrict__ x, const unsigned short* __restrict__ Wbf,
    const float* __restrict__ conv_b, float* __restrict__ h_out,
    float* __restrict__ psum, unsigned* __restrict__ pmaxe)
{
  __shared__ __align__(16) unsigned short Bs[64 * 264];
  const int bid = blockIdx.x;
  const int b = bid / 49, tile = bid - 49 * (bid / 49);
  const int hw0 = tile * 64;
  const int t = threadIdx.x;

  { // stage x[b, :, hw0..hw0+64) transposed into LDS as bf16: Bs[hw*264 + c]
    int g = t & 127, half = t >> 7;
    const float* p0 = x + ((size_t)(b * 256 + 2 * g)) * HW + hw0 + half * 32;
    const float* p1 = p0 + HW;
    unsigned* Bd = (unsigned*)Bs;
#pragma unroll
    for (int i = 0; i < 32; i += 4) {
      float4 a4 = *(const float4*)(p0 + i);
      float4 c4 = *(const float4*)(p1 + i);
      int hw = half * 32 + i;
      Bd[(hw + 0) * 132 + g] = pack2(a4.x, c4.x);
      Bd[(hw + 1) * 132 + g] = pack2(a4.y, c4.y);
      Bd[(hw + 2) * 132 + g] = pack2(a4.z, c4.z);
      Bd[(hw + 3) * 132 + g] = pack2(a4.w, c4.w);
    }
  }
  __syncthreads();

  const int w = t >> 6, l = t & 63, hq = l & 15, g2 = l >> 4;
  const int wm0 = w * 64;
  const f32x4 vzero = {0.f, 0.f, 0.f, 0.f};
  f32x4 acc[4][4];
#pragma unroll
  for (int mi = 0; mi < 4; ++mi)
#pragma unroll
    for (int ni = 0; ni < 4; ++ni) acc[mi][ni] = vzero;

#pragma unroll
  for (int ks = 0; ks < 8; ++ks) {
    short8 a[4], bv[4];
#pragma unroll
    for (int mi = 0; mi < 4; ++mi)
      a[mi] = *(const short8*)(Wbf + (size_t)(wm0 + mi * 16 + hq) * 256 + ks * 32 + g2 * 8);
#pragma unroll
    for (int ni = 0; ni < 4; ++ni)
      bv[ni] = *(const short8*)(Bs + (ni * 16 + hq) * 264 + ks * 32 + g2 * 8);
#pragma unroll
    for (int mi = 0; mi < 4; ++mi)
#pragma unroll
      for (int ni = 0; ni < 4; ++ni)
        acc[mi][ni] = __builtin_amdgcn_mfma_f32_16x16x32_bf16(a[mi], bv[ni], acc[mi][ni], 0, 0, 0);
  }

#pragma unroll
  for (int mi = 0; mi < 4; ++mi) {
#pragma unroll
    for (int r = 0; r < 4; ++r) {
      int o = wm0 + mi * 16 + g2 * 4 + r;
      float bias = conv_b[o];
      float v[4];
#pragma unroll
      for (int ni = 0; ni < 4; ++ni) {
        float s = acc[mi][ni][r] + bias;
        v[ni] = 0.5f * s * (1.0f + erff(s * 0.70710678118654752f));
      }
      float* hp = h_out + ((size_t)(b * 256 + o)) * HW + hw0;
      hp[0 * 16 + hq] = v[0];
      hp[1 * 16 + hq] = v[1];
      hp[2 * 16 + hq] = v[2];
      hp[3 * 16 + hq] = v[3];
      float sm = v[0] + v[1] + v[2] + v[3];
      float mx = fmaxf(fmaxf(v[0], v[1]), fmaxf(v[2], v[3]));
#pragma unroll
      for (int d = 1; d < 16; d <<= 1) {
        sm += __shfl_xor(sm, d);
        mx = fmaxf(mx, __shfl_xor(mx, d));
      }
      if (hq == 0) {
        atomicAdd(psum + b * 256 + o, sm);
        atomicMax(pmaxe + b * 256 + o, fenc(mx));
      }
    }
  }
}

// ---------------- K2: channel attention FCs ----------------
__global__ __launch_bounds__(256) void k2_att(
    const float* __restrict__ psum, const unsigned* __restrict__ pmaxe,
    const float* __restrict__ fc1_w, const float* __restrict__ fc1_b,
    const float* __restrict__ fc2_w, const float* __restrict__ fc2_b,
    float* __restrict__ att)
{
  int b = blockIdx.x, t = threadIdx.x;
  __shared__ float hA[64], hM[64];
  if (t < 128) {
    int j = t & 63;
    bool ism = t >= 64;
    float s = fc1_b[j];
    for (int c = 0; c < 256; ++c) {
      float p = ism ? fdec(pmaxe[b * 256 + c]) : (psum[b * 256 + c] * (1.f / 3136.f));
      s += p * fc1_w[j * 256 + c];
    }
    s = fmaxf(s, 0.f);
    if (ism) hM[j] = s; else hA[j] = s;
  }
  __syncthreads();
  float s1 = fc2_b[t], s2 = s1;
  for (int j = 0; j < 64; ++j) {
    float wv = fc2_w[t * 64 + j];
    s1 += hA[j] * wv;
    s2 += hM[j] * wv;
  }
  att[b * 256 + t] = 1.f / (1.f + expf(-s1)) + 1.f / (1.f + expf(-s2));
}

// ---------------- K34: dw5x5(att*h) -> [LDS] -> 3 separable branches -> xs ----------------
__global__ __launch_bounds__(256) void k34_dw(
    const float* __restrict__ h_in, const float* __restrict__ att,
    const float* __restrict__ w5, const float* __restrict__ b5,
    const float* __restrict__ w1x7, const float* __restrict__ b1x7,
    const float* __restrict__ w7x1, const float* __restrict__ b7x1,
    const float* __restrict__ w1x11, const float* __restrict__ b1x11,
    const float* __restrict__ w11x1, const float* __restrict__ b11x1,
    const float* __restrict__ w1x21, const float* __restrict__ b1x21,
    const float* __restrict__ w21x1, const float* __restrict__ b21x1,
    float* __restrict__ xs_out)
{
  __shared__ __align__(16) float Sx[56 * 80];   // phase0: first 3600 floats = halo'd hs (60x60)
  __shared__ __align__(16) float T1[56 * 56], T2[56 * 56], T3[56 * 56];
  __shared__ float wk[78];  // [0,7)=w1x7 [7,14)=w7x1 [14,25)=w1x11 [25,36)=w11x1 [36,57)=w1x21 [57,78)=w21x1
  __shared__ float wk5[25];

  const int bid = blockIdx.x;
  const int b = bid >> 8, c = bid & 255;
  const int t = threadIdx.x;
  const size_t plane = (size_t)(b * 256 + c) * HW;

  if (t < 25) wk5[t] = w5[c * 25 + t];
  if (t >= 32 && t < 110) {
    int k = t - 32;
    float v;
    if (k < 7) v = w1x7[c * 7 + k];
    else if (k < 14) v = w7x1[c * 7 + k - 7];
    else if (k < 25) v = w1x11[c * 11 + k - 14];
    else if (k < 36) v = w11x1[c * 11 + k - 25];
    else if (k < 57) v = w1x21[c * 21 + k - 36];
    else v = w21x1[c * 21 + k - 57];
    wk[k] = v;
  }
  { // stage halo'd hs (rows/cols -2..58) into S5 = Sx[0..3600)
    float a = att[b * 256 + c];
    const float* hp = h_in + plane;
    for (int idx = t; idx < 3600; idx += 256) {
      int ly = idx / 60, lx = idx - ly * 60;
      int gy = ly - 2, gx = lx - 2;
      float v = 0.f;
      if ((unsigned)gy < 56u && (unsigned)gx < 56u) v = a * hp[gy * 56 + gx];
      Sx[idx] = v;
    }
  }
  __syncthreads();

  // dw5x5 -> registers (x_init), 4-row blocks per task
  float xv[4][4];
  float bias5 = b5[c];
#pragma unroll
  for (int it = 0; it < 4; ++it) {
    int task = t + it * 256;
    if (task < 784) {
      int yq = task / 56, xx = task - yq * 56;
      int y0 = yq * 4;
      float a4[4] = {bias5, bias5, bias5, bias5};
#pragma unroll
      for (int kx = 0; kx < 5; ++kx) {
        float col[8];
#pragma unroll
        for (int ry = 0; ry < 8; ++ry) col[ry] = Sx[(y0 + ry) * 60 + xx + kx];
#pragma unroll
        for (int d = 0; d < 4; ++d)
#pragma unroll
          for (int ky = 0; ky < 5; ++ky) a4[d] += col[d + ky] * wk5[ky * 5 + kx];
      }
#pragma unroll
      for (int d = 0; d < 4; ++d) xv[it][d] = a4[d];
    }
  }
  __syncthreads();

  // store x_init into padded Sx[56][80] (data at col offset 12), zero pads
#pragma unroll
  for (int it = 0; it < 4; ++it) {
    int task = t + it * 256;
    if (task < 784) {
      int yq = task / 56, xx = task - yq * 56;
      int y0 = yq * 4;
#pragma unroll
      for (int d = 0; d < 4; ++d) Sx[(y0 + d) * 80 + 12 + xx] = xv[it][d];
    }
  }
  for (int i = t; i < 56 * 24; i += 256) {
    int y = i / 24, j = i - y * 24;
    int lx = (j < 12) ? j : (56 + j);
    Sx[y * 80 + lx] = 0.f;
  }
  __syncthreads();

  // phase A: horizontal convs, 4 consecutive x per task, window of 28 via float4
  float bb1 = b1x7[c], bb2 = b1x11[c], bb3 = b1x21[c];
  for (int task = t; task < 784; task += 256) {
    int y = task / 14, xq = task - y * 14;
    int x0 = xq * 4;
    float win[28];
    const float* rp = Sx + y * 80 + x0;  // = xin[y][x0-12 ...]
#pragma unroll
    for (int j = 0; j < 28; j += 4) {
      float4 q = *(const float4*)(rp + j);
      win[j] = q.x; win[j + 1] = q.y; win[j + 2] = q.z; win[j + 3] = q.w;
    }
    float o1[4], o2[4], o3[4];
#pragma unroll
    for (int d = 0; d < 4; ++d) { o1[d] = bb1; o2[d] = bb2; o3[d] = bb3; }
#pragma unroll
    for (int k = 0; k < 7; ++k) {
      float wv = wk[k];
#pragma unroll
      for (int d = 0; d < 4; ++d) o1[d] += win[9 + d + k] * wv;
    }
#pragma unroll
    for (int k = 0; k < 11; ++k) {
      float wv = wk[14 + k];
#pragma unroll
      for (int d = 0; d < 4; ++d) o2[d] += win[7 + d + k] * wv;
    }
#pragma unroll
    for (int k = 0; k < 21; ++k) {
      float wv = wk[36 + k];
#pragma unroll
      for (int d = 0; d < 4; ++d) o3[d] += win[2 + d + k] * wv;
    }
    float4 q1, q2, q3;
    q1.x = o1[0]; q1.y = o1[1]; q1.z = o1[2]; q1.w = o1[3];
    q2.x = o2[0]; q2.y = o2[1]; q2.z = o2[2]; q2.w = o2[3];
    q3.x = o3[0]; q3.y = o3[1]; q3.z = o3[2]; q3.w = o3[3];
    *(float4*)&T1[y * 56 + x0] = q1;
    *(float4*)&T2[y * 56 + x0] = q2;
    *(float4*)&T3[y * 56 + x0] = q3;
  }
  __syncthreads();

  // phase B: vertical convs + sum, 4 consecutive y per task
  float vb = b7x1[c] + b11x1[c] + b21x1[c];
  float* op = xs_out + plane;
  for (int task = t; task < 784; task += 256) {
    int yq = task / 56, xx = task - yq * 56;
    int y0 = yq * 4;
    float r4[4];
#pragma unroll
    for (int d = 0; d < 4; ++d) r4[d] = Sx[(y0 + d) * 80 + 12 + xx] + vb;
    {
      float cw[10];
#pragma unroll
      for (int j = 0; j < 10; ++j) {
        int row = y0 - 3 + j;
        cw[j] = ((unsigned)row < 56u) ? T1[row * 56 + xx] : 0.f;
      }
#pragma unroll
      for (int k = 0; k < 7; ++k) {
        float wv = wk[7 + k];
#pragma unroll
        for (int d = 0; d < 4; ++d) r4[d] += cw[d + k] * wv;
      }
    }
    {
      float cw[14];
#pragma unroll
      for (int j = 0; j < 14; ++j) {
        int row = y0 - 5 + j;
        cw[j] = ((unsigned)row < 56u) ? T2[row * 56 + xx] : 0.f;
      }
#pragma unroll
      for (int k = 0; k < 11; ++k) {
        float wv = wk[25 + k];
#pragma unroll
        for (int d = 0; d < 4; ++d) r4[d] += cw[d + k] * wv;
      }
    }
    {
      float cw[24];
#pragma unroll
      for (int j = 0; j < 24; ++j) {
        int row = y0 - 10 + j;
        cw[j] = ((unsigned)row < 56u) ? T3[row * 56 + xx] : 0.f;
      }
#pragma unroll
      for (int k = 0; k < 21; ++k) {
        float wv = wk[57 + k];
#pragma unroll
        for (int d = 0; d < 4; ++d) r4[d] += cw[d + k] * wv;
      }
    }
#pragma unroll
    for (int d = 0; d < 4; ++d) op[(y0 + d) * 56 + xx] = r4[d];
  }
}

// ---------------- K5: spatial_att = W*xs+b ; out = sa*(att*h) ; result = W*out+b ----------------
__global__ __launch_bounds__(256) void k5_final(
    const float* __restrict__ xs, const unsigned short* __restrict__ Wbf,
    const float* __restrict__ conv_b, const float* __restrict__ att,
    const float* __restrict__ h_in, float* __restrict__ outp)
{
  __shared__ __align__(16) unsigned short Bs[64 * 264];
  const int bid = blockIdx.x;
  const int b = bid / 49, tile = bid - 49 * (bid / 49);
  const int hw0 = tile * 64;
  const int t = threadIdx.x;

  { // stage xs transposed bf16
    int g = t & 127, half = t >> 7;
    const float* p0 = xs + ((size_t)(b * 256 + 2 * g)) * HW + hw0 + half * 32;
    const float* p1 = p0 + HW;
    unsigned* Bd = (unsigned*)Bs;
#pragma unroll
    for (int i = 0; i < 32; i += 4) {
      float4 a4 = *(const float4*)(p0 + i);
      float4 c4 = *(const float4*)(p1 + i);
      int hw = half * 32 + i;
      Bd[(hw + 0) * 132 + g] = pack2(a4.x, c4.x);
      Bd[(hw + 1) * 132 + g] = pack2(a4.y, c4.y);
      Bd[(hw + 2) * 132 + g] = pack2(a4.z, c4.z);
      Bd[(hw + 3) * 132 + g] = pack2(a4.w, c4.w);
    }
  }
  __syncthreads();

  const int w = t >> 6, l = t & 63, hq = l & 15, g2 = l >> 4;
  const int wm0 = w * 64;
  const f32x4 vzero = {0.f, 0.f, 0.f, 0.f};
  f32x4 acc[4][4];
#pragma unroll
  for (int mi = 0; mi < 4; ++mi)
#pragma unroll
    for (int ni = 0; ni < 4; ++ni) acc[mi][ni] = vzero;

#pragma unroll
  for (int ks = 0; ks < 8; ++ks) {
    short8 a[4], bv[4];
#pragma unroll
    for (int mi = 0; mi < 4; ++mi)
      a[mi] = *(const short8*)(Wbf + (size_t)(wm0 + mi * 16 + hq) * 256 + ks * 32 + g2 * 8);
#pragma unroll
    for (int ni = 0; ni < 4; ++ni)
      bv[ni] = *(const short8*)(Bs + (ni * 16 + hq) * 264 + ks * 32 + g2 * 8);
#pragma unroll
    for (int mi = 0; mi < 4; ++mi)
#pragma unroll
      for (int ni = 0; ni < 4; ++ni)
        acc[mi][ni] = __builtin_amdgcn_mfma_f32_16x16x32_bf16(a[mi], bv[ni], acc[mi][ni], 0, 0, 0);
  }
  __syncthreads();  // all matmul1 LDS reads done

  // out = (sa+bias) * att * h -> write transposed bf16 into Bs
#pragma unroll
  for (int mi = 0; mi < 4; ++mi) {
#pragma unroll
    for (int r = 0; r < 4; ++r) {
      int o = wm0 + mi * 16 + g2 * 4 + r;
      float bias = conv_b[o];
      float av = att[b * 256 + o];
      const float* hp = h_in + ((size_t)(b * 256 + o)) * HW + hw0;
#pragma unroll
      for (int ni = 0; ni < 4; ++ni) {
        float sa = acc[mi][ni][r] + bias;
        float ov = sa * (av * hp[ni * 16 + hq]);
        Bs[(ni * 16 + hq) * 264 + o] = bfb(ov);
      }
    }
  }
  __syncthreads();

  f32x4 acc2[4][4];
#pragma unroll
  for (int mi = 0; mi < 4; ++mi)
#pragma unroll
    for (int ni = 0; ni < 4; ++ni) acc2[mi][ni] = vzero;
#pragma unroll
  for (int ks = 0; ks < 8; ++ks) {
    short8 a[4], bv[4];
#pragma unroll
    for (int mi = 0; mi < 4; ++mi)
      a[mi] = *(const short8*)(Wbf + (size_t)(wm0 + mi * 16 + hq) * 256 + ks * 32 + g2 * 8);
#pragma unroll
    for (int ni = 0; ni < 4; ++ni)
      bv[ni] = *(const short8*)(Bs + (ni * 16 + hq) * 264 + ks * 32 + g2 * 8);
#pragma unroll
    for (int mi = 0; mi < 4; ++mi)
#pragma unroll
      for (int ni = 0; ni < 4; ++ni)
        acc2[mi][ni] = __builtin_amdgcn_mfma_f32_16x16x32_bf16(a[mi], bv[ni], acc2[mi][ni], 0, 0, 0);
  }

#pragma unroll
  for (int mi = 0; mi < 4; ++mi) {
#pragma unroll
    for (int r = 0; r < 4; ++r) {
      int o = wm0 + mi * 16 + g2 * 4 + r;
      float bias = conv_b[o];
      float* op = outp + ((size_t)(b * 256 + o)) * HW + hw0;
#pragma unroll
      for (int ni = 0; ni < 4; ++ni) op[ni * 16 + hq] = acc2[mi][ni][r] + bias;
    }
  }
}

extern "C" void kernel_launch(void* const* d_in, const int* in_sizes, int n_in,
                              void* d_out, int out_size, void* d_ws, size_t ws_size,
                              hipStream_t stream) {
  const float* x      = (const float*)d_in[0];
  const float* conv_w = (const float*)d_in[1];
  const float* conv_b = (const float*)d_in[2];
  const float* fc1_w  = (const float*)d_in[3];
  const float* fc1_b  = (const float*)d_in[4];
  const float* fc2_w  = (const float*)d_in[5];
  const float* fc2_b  = (const float*)d_in[6];
  const float* w5     = (const float*)d_in[7];
  const float* b5     = (const float*)d_in[8];
  const float* w1x7   = (const float*)d_in[9];
  const float* b1x7   = (const float*)d_in[10];
  const float* w7x1   = (const float*)d_in[11];
  const float* b7x1   = (const float*)d_in[12];
  const float* w1x11  = (const float*)d_in[13];
  const float* b1x11  = (const float*)d_in[14];
  const float* w11x1  = (const float*)d_in[15];
  const float* b11x1  = (const float*)d_in[16];
  const float* w1x21  = (const float*)d_in[17];
  const float* b1x21  = (const float*)d_in[18];
  const float* w21x1  = (const float*)d_in[19];
  const float* b21x1  = (const float*)d_in[20];
  float* out = (float*)d_out;

  char* ws = (char*)d_ws;
  unsigned short* Wbf = (unsigned short*)(ws);            // 131072 B
  float* psum   = (float*)(ws + 131072);                  // 16384 B
  unsigned* pme = (unsigned*)(ws + 147456);               // 16384 B
  float* attb   = (float*)(ws + 163840);                  // 16384 B
  float* xbuf   = (float*)(ws + 180224);                  // 51380224 B (xs)

  k0_init<<<256, 256, 0, stream>>>(conv_w, Wbf, psum, pme);
  k1_conv_gelu_pool<<<784, 256, 0, stream>>>(x, Wbf, conv_b, out, psum, pme);
  k2_att<<<16, 256, 0, stream>>>(psum, pme, fc1_w, fc1_b, fc2_w, fc2_b, attb);
  k34_dw<<<4096, 256, 0, stream>>>(out, attb, w5, b5, w1x7, b1x7, w7x1, b7x1,
                                   w1x11, b1x11, w11x1, b11x1, w1x21, b1x21,
                                   w21x1, b21x1, xbuf);
  k5_final<<<784, 256, 0, stream>>>(xbuf, Wbf, conv_b, attb, out, out);
}

// Round 2
// 257.225 us; speedup vs baseline: 1.0775x; 1.0775x over previous
//
#include <hip/hip_runtime.h>
#include <hip/hip_bf16.h>

#define HW 3136
#define NB 16

typedef float f32x4 __attribute__((ext_vector_type(4)));
typedef short short8 __attribute__((ext_vector_type(8)));

__device__ inline unsigned short bfb(float f) {
  union { __hip_bfloat16 h; unsigned short u; } cv;
  cv.h = __float2bfloat16(f);
  return cv.u;
}
__device__ inline unsigned pack2(float lo, float hi) {
  return (unsigned)bfb(lo) | ((unsigned)bfb(hi) << 16);
}
// order-preserving float<->uint encode for atomicMax
__device__ inline unsigned fenc(float f) {
  unsigned u = __float_as_uint(f);
  return (u & 0x80000000u) ? ~u : (u | 0x80000000u);
}
__device__ inline float fdec(unsigned e) {
  return (e & 0x80000000u) ? __uint_as_float(e & 0x7FFFFFFFu) : __uint_as_float(~e);
}
__device__ inline float bf2f(unsigned short u) {
  return __uint_as_float((unsigned)u << 16);
}

// ---------------- K0: convert W to bf16, zero pool buffers ----------------
__global__ __launch_bounds__(256) void k0_init(const float* __restrict__ conv_w,
                                               unsigned short* __restrict__ Wbf,
                                               float* __restrict__ psum,
                                               unsigned* __restrict__ pmaxe) {
  int i = blockIdx.x * 256 + threadIdx.x;
  Wbf[i] = bfb(conv_w[i]);
  if (i < 4096) psum[i] = 0.f;
  else if (i < 8192) pmaxe[i - 4096] = 0u;
}

// ---------------- K1: conv1x1 + bias + GELU -> h ; fused channel pooling ----------------
__global__ __launch_bounds__(256) void k1_conv_gelu_pool(
    const float* __restrict__ x, const unsigned short* __restrict__ Wbf,
    const float* __restrict__ conv_b, float* __restrict__ h_out,
    float* __restrict__ psum, unsigned* __restrict__ pmaxe)
{
  __shared__ __align__(16) unsigned short Bs[64 * 264];
  const int bid = blockIdx.x;
  const int b = bid / 49, tile = bid - 49 * (bid / 49);
  const int hw0 = tile * 64;
  const int t = threadIdx.x;

  {
    int g = t & 127, half = t >> 7;
    const float* p0 = x + ((size_t)(b * 256 + 2 * g)) * HW + hw0 + half * 32;
    const float* p1 = p0 + HW;
    unsigned* Bd = (unsigned*)Bs;
#pragma unroll
    for (int i = 0; i < 32; i += 4) {
      float4 a4 = *(const float4*)(p0 + i);
      float4 c4 = *(const float4*)(p1 + i);
      int hw = half * 32 + i;
      Bd[(hw + 0) * 132 + g] = pack2(a4.x, c4.x);
      Bd[(hw + 1) * 132 + g] = pack2(a4.y, c4.y);
      Bd[(hw + 2) * 132 + g] = pack2(a4.z, c4.z);
      Bd[(hw + 3) * 132 + g] = pack2(a4.w, c4.w);
    }
  }
  __syncthreads();

  const int w = t >> 6, l = t & 63, hq = l & 15, g2 = l >> 4;
  const int wm0 = w * 64;
  const f32x4 vzero = {0.f, 0.f, 0.f, 0.f};
  f32x4 acc[4][4];
#pragma unroll
  for (int mi = 0; mi < 4; ++mi)
#pragma unroll
    for (int ni = 0; ni < 4; ++ni) acc[mi][ni] = vzero;

#pragma unroll
  for (int ks = 0; ks < 8; ++ks) {
    short8 a[4], bv[4];
#pragma unroll
    for (int mi = 0; mi < 4; ++mi)
      a[mi] = *(const short8*)(Wbf + (size_t)(wm0 + mi * 16 + hq) * 256 + ks * 32 + g2 * 8);
#pragma unroll
    for (int ni = 0; ni < 4; ++ni)
      bv[ni] = *(const short8*)(Bs + (ni * 16 + hq) * 264 + ks * 32 + g2 * 8);
#pragma unroll
    for (int mi = 0; mi < 4; ++mi)
#pragma unroll
      for (int ni = 0; ni < 4; ++ni)
        acc[mi][ni] = __builtin_amdgcn_mfma_f32_16x16x32_bf16(a[mi], bv[ni], acc[mi][ni], 0, 0, 0);
  }

#pragma unroll
  for (int mi = 0; mi < 4; ++mi) {
#pragma unroll
    for (int r = 0; r < 4; ++r) {
      int o = wm0 + mi * 16 + g2 * 4 + r;
      float bias = conv_b[o];
      float v[4];
#pragma unroll
      for (int ni = 0; ni < 4; ++ni) {
        float s = acc[mi][ni][r] + bias;
        v[ni] = 0.5f * s * (1.0f + erff(s * 0.70710678118654752f));
      }
      float* hp = h_out + ((size_t)(b * 256 + o)) * HW + hw0;
      hp[0 * 16 + hq] = v[0];
      hp[1 * 16 + hq] = v[1];
      hp[2 * 16 + hq] = v[2];
      hp[3 * 16 + hq] = v[3];
      float sm = v[0] + v[1] + v[2] + v[3];
      float mx = fmaxf(fmaxf(v[0], v[1]), fmaxf(v[2], v[3]));
#pragma unroll
      for (int d = 1; d < 16; d <<= 1) {
        sm += __shfl_xor(sm, d);
        mx = fmaxf(mx, __shfl_xor(mx, d));
      }
      if (hq == 0) {
        atomicAdd(psum + b * 256 + o, sm);
        atomicMax(pmaxe + b * 256 + o, fenc(mx));
      }
    }
  }
}

// ---------------- K2: channel attention FCs ----------------
__global__ __launch_bounds__(256) void k2_att(
    const float* __restrict__ psum, const unsigned* __restrict__ pmaxe,
    const float* __restrict__ fc1_w, const float* __restrict__ fc1_b,
    const float* __restrict__ fc2_w, const float* __restrict__ fc2_b,
    float* __restrict__ att)
{
  int b = blockIdx.x, t = threadIdx.x;
  __shared__ float hA[64], hM[64];
  if (t < 128) {
    int j = t & 63;
    bool ism = t >= 64;
    float s = fc1_b[j];
    for (int c = 0; c < 256; ++c) {
      float p = ism ? fdec(pmaxe[b * 256 + c]) : (psum[b * 256 + c] * (1.f / 3136.f));
      s += p * fc1_w[j * 256 + c];
    }
    s = fmaxf(s, 0.f);
    if (ism) hM[j] = s; else hA[j] = s;
  }
  __syncthreads();
  float s1 = fc2_b[t], s2 = s1;
  for (int j = 0; j < 64; ++j) {
    float wv = fc2_w[t * 64 + j];
    s1 += hA[j] * wv;
    s2 += hM[j] * wv;
  }
  att[b * 256 + t] = 1.f / (1.f + expf(-s1)) + 1.f / (1.f + expf(-s2));
}

// ---------------- K34 v2: dw5x5(att*h) -> branches sequential with single bf16 temp ----------------
// LDS plan (~39.4 KB -> 4 blocks/CU, 16 waves/CU):
//   B0  fp32 [4480]: halo input [60][60] (P0-P1), then padded x_init [56][80] (data at col+12)
//   Tt  bf16 [56][76] transposed branch temp: Tt[x*76 + (y+10)], rows 0..9 & 66..75 zero pads
//   Acc fp32 [56][56]: x_init + vertical biases, accumulates branch outputs
template<int KLEN, int WOFF_H, int WOFF_V, bool LAST>
__device__ __forceinline__ void do_branch(float* B0, unsigned short* Tt, float* Acc,
                                          const float* wk, float bb, int t, float* op)
{
  constexpr int HALF = KLEN / 2;
  // phase A: horizontal conv, row-major tasks (4 consecutive x)
  for (int task = t; task < 784; task += 256) {
    int y = task / 14, xq = task - y * 14, x0 = xq * 4;
    float win[28];
    const float* rp = B0 + y * 80 + x0;
#pragma unroll
    for (int j = 0; j < 28; j += 4) {
      float4 q = *(const float4*)(rp + j);
      win[j] = q.x; win[j + 1] = q.y; win[j + 2] = q.z; win[j + 3] = q.w;
    }
    float o[4] = {bb, bb, bb, bb};
#pragma unroll
    for (int k = 0; k < KLEN; ++k) {
      float wv = wk[WOFF_H + k];
#pragma unroll
      for (int d = 0; d < 4; ++d) o[d] += win[(12 - HALF) + d + k] * wv;
    }
#pragma unroll
    for (int d = 0; d < 4; ++d) Tt[(x0 + d) * 76 + (y + 10)] = bfb(o[d]);
  }
  __syncthreads();
  // phase B: vertical conv, col-major tasks (4 consecutive y), unpredicated b64 window reads
  for (int task = t; task < 784; task += 256) {
    int yq = task / 56, xx = task - yq * 56, y0 = yq * 4;
    constexpr int RB = (KLEN == 21) ? 0 : 4;   // window base = y0 + RB (4-aligned)
    constexpr int NL = (KLEN == 21) ? 24 : 16; // rows loaded
    float cw[NL];
#pragma unroll
    for (int j = 0; j < NL; j += 4) {
      ushort4 q4 = *(const ushort4*)&Tt[xx * 76 + y0 + RB + j];
      cw[j]     = bf2f(q4.x);
      cw[j + 1] = bf2f(q4.y);
      cw[j + 2] = bf2f(q4.z);
      cw[j + 3] = bf2f(q4.w);
    }
    float r4[4];
#pragma unroll
    for (int d = 0; d < 4; ++d) r4[d] = Acc[(y0 + d) * 56 + xx];
#pragma unroll
    for (int k = 0; k < KLEN; ++k) {
      float wv = wk[WOFF_V + k];
#pragma unroll
      for (int d = 0; d < 4; ++d) r4[d] += cw[(10 - HALF - RB) + d + k] * wv;
    }
    if (LAST) {
#pragma unroll
      for (int d = 0; d < 4; ++d) op[(y0 + d) * 56 + xx] = r4[d];
    } else {
#pragma unroll
      for (int d = 0; d < 4; ++d) Acc[(y0 + d) * 56 + xx] = r4[d];
    }
  }
  if (!LAST) __syncthreads();
}

__global__ __launch_bounds__(256) void k34_dw(
    const float* __restrict__ h_in, const float* __restrict__ att,
    const float* __restrict__ w5, const float* __restrict__ b5,
    const float* __restrict__ w1x7, const float* __restrict__ b1x7,
    const float* __restrict__ w7x1, const float* __restrict__ b7x1,
    const float* __restrict__ w1x11, const float* __restrict__ b1x11,
    const float* __restrict__ w11x1, const float* __restrict__ b11x1,
    const float* __restrict__ w1x21, const float* __restrict__ b1x21,
    const float* __restrict__ w21x1, const float* __restrict__ b21x1,
    float* __restrict__ xs_out)
{
  __shared__ __align__(16) float B0[4480];
  __shared__ __align__(16) unsigned short Tt[56 * 76];
  __shared__ __align__(16) float Acc[3136];
  __shared__ float wk[78];  // [0,7)=w1x7 [7,14)=w7x1 [14,25)=w1x11 [25,36)=w11x1 [36,57)=w1x21 [57,78)=w21x1
  __shared__ float wk5[25];

  const int bid = blockIdx.x;
  const int b = bid >> 8, c = bid & 255;
  const int t = threadIdx.x;
  const size_t plane = (size_t)(b * 256 + c) * HW;

  if (t < 25) wk5[t] = w5[c * 25 + t];
  if (t >= 32 && t < 110) {
    int k = t - 32;
    float v;
    if (k < 7) v = w1x7[c * 7 + k];
    else if (k < 14) v = w7x1[c * 7 + k - 7];
    else if (k < 25) v = w1x11[c * 11 + k - 14];
    else if (k < 36) v = w11x1[c * 11 + k - 25];
    else if (k < 57) v = w1x21[c * 21 + k - 36];
    else v = w21x1[c * 21 + k - 57];
    wk[k] = v;
  }
  { // P0: stage halo'd a*h (rows/cols -2..58) into B0[0..3600)
    float a = att[b * 256 + c];
    const float* hp = h_in + plane;
    for (int idx = t; idx < 3600; idx += 256) {
      int ly = idx / 60, lx = idx - ly * 60;
      int gy = ly - 2, gx = lx - 2;
      float v = 0.f;
      if ((unsigned)gy < 56u && (unsigned)gx < 56u) v = a * hp[gy * 56 + gx];
      B0[idx] = v;
    }
  }
  __syncthreads();

  // P1: dw5x5 -> registers (x_init)
  float xv[4][4];
  float bias5 = b5[c];
#pragma unroll
  for (int it = 0; it < 4; ++it) {
    int task = t + it * 256;
    if (task < 784) {
      int yq = task / 56, xx = task - yq * 56;
      int y0 = yq * 4;
      float a4[4] = {bias5, bias5, bias5, bias5};
#pragma unroll
      for (int kx = 0; kx < 5; ++kx) {
        float col[8];
#pragma unroll
        for (int ry = 0; ry < 8; ++ry) col[ry] = B0[(y0 + ry) * 60 + xx + kx];
#pragma unroll
        for (int d = 0; d < 4; ++d)
#pragma unroll
          for (int ky = 0; ky < 5; ++ky) a4[d] += col[d + ky] * wk5[ky * 5 + kx];
      }
#pragma unroll
      for (int d = 0; d < 4; ++d) xv[it][d] = a4[d];
    }
  }
  __syncthreads();

  // P2: scatter x_init (padded fp32), init Acc = x_init + vertical biases, zero pads
  float vb = b7x1[c] + b11x1[c] + b21x1[c];
#pragma unroll
  for (int it = 0; it < 4; ++it) {
    int task = t + it * 256;
    if (task < 784) {
      int yq = task / 56, xx = task - yq * 56;
      int y0 = yq * 4;
#pragma unroll
      for (int d = 0; d < 4; ++d) {
        B0[(y0 + d) * 80 + 12 + xx] = xv[it][d];
        Acc[(y0 + d) * 56 + xx] = xv[it][d] + vb;
      }
    }
  }
  for (int i = t; i < 56 * 24; i += 256) {  // B0 horizontal pads
    int y = i / 24, j = i - y * 24;
    int lx = (j < 12) ? j : (56 + j);
    B0[y * 80 + lx] = 0.f;
  }
  for (int i = t; i < 56 * 20; i += 256) {  // Tt vertical pads (once; branches only write r in [10,66))
    int x = i / 20, j = i - x * 20;
    int r = (j < 10) ? j : (56 + j);
    Tt[x * 76 + r] = 0;
  }
  __syncthreads();

  float* op = xs_out + plane;
  do_branch<7, 0, 7, false>(B0, Tt, Acc, wk, b1x7[c], t, op);
  do_branch<11, 14, 25, false>(B0, Tt, Acc, wk, b1x11[c], t, op);
  do_branch<21, 36, 57, true>(B0, Tt, Acc, wk, b1x21[c], t, op);
}

// ---------------- K5: spatial_att = W*xs+b ; out = sa*(att*h) ; result = W*out+b ----------------
__global__ __launch_bounds__(256) void k5_final(
    const float* __restrict__ xs, const unsigned short* __restrict__ Wbf,
    const float* __restrict__ conv_b, const float* __restrict__ att,
    const float* __restrict__ h_in, float* __restrict__ outp)
{
  __shared__ __align__(16) unsigned short Bs[64 * 264];
  const int bid = blockIdx.x;
  const int b = bid / 49, tile = bid - 49 * (bid / 49);
  const int hw0 = tile * 64;
  const int t = threadIdx.x;

  {
    int g = t & 127, half = t >> 7;
    const float* p0 = xs + ((size_t)(b * 256 + 2 * g)) * HW + hw0 + half * 32;
    const float* p1 = p0 + HW;
    unsigned* Bd = (unsigned*)Bs;
#pragma unroll
    for (int i = 0; i < 32; i += 4) {
      float4 a4 = *(const float4*)(p0 + i);
      float4 c4 = *(const float4*)(p1 + i);
      int hw = half * 32 + i;
      Bd[(hw + 0) * 132 + g] = pack2(a4.x, c4.x);
      Bd[(hw + 1) * 132 + g] = pack2(a4.y, c4.y);
      Bd[(hw + 2) * 132 + g] = pack2(a4.z, c4.z);
      Bd[(hw + 3) * 132 + g] = pack2(a4.w, c4.w);
    }
  }
  __syncthreads();

  const int w = t >> 6, l = t & 63, hq = l & 15, g2 = l >> 4;
  const int wm0 = w * 64;
  const f32x4 vzero = {0.f, 0.f, 0.f, 0.f};
  f32x4 acc[4][4];
#pragma unroll
  for (int mi = 0; mi < 4; ++mi)
#pragma unroll
    for (int ni = 0; ni < 4; ++ni) acc[mi][ni] = vzero;

#pragma unroll
  for (int ks = 0; ks < 8; ++ks) {
    short8 a[4], bv[4];
#pragma unroll
    for (int mi = 0; mi < 4; ++mi)
      a[mi] = *(const short8*)(Wbf + (size_t)(wm0 + mi * 16 + hq) * 256 + ks * 32 + g2 * 8);
#pragma unroll
    for (int ni = 0; ni < 4; ++ni)
      bv[ni] = *(const short8*)(Bs + (ni * 16 + hq) * 264 + ks * 32 + g2 * 8);
#pragma unroll
    for (int mi = 0; mi < 4; ++mi)
#pragma unroll
      for (int ni = 0; ni < 4; ++ni)
        acc[mi][ni] = __builtin_amdgcn_mfma_f32_16x16x32_bf16(a[mi], bv[ni], acc[mi][ni], 0, 0, 0);
  }
  __syncthreads();

#pragma unroll
  for (int mi = 0; mi < 4; ++mi) {
#pragma unroll
    for (int r = 0; r < 4; ++r) {
      int o = wm0 + mi * 16 + g2 * 4 + r;
      float bias = conv_b[o];
      float av = att[b * 256 + o];
      const float* hp = h_in + ((size_t)(b * 256 + o)) * HW + hw0;
#pragma unroll
      for (int ni = 0; ni < 4; ++ni) {
        float sa = acc[mi][ni][r] + bias;
        float ov = sa * (av * hp[ni * 16 + hq]);
        Bs[(ni * 16 + hq) * 264 + o] = bfb(ov);
      }
    }
  }
  __syncthreads();

  f32x4 acc2[4][4];
#pragma unroll
  for (int mi = 0; mi < 4; ++mi)
#pragma unroll
    for (int ni = 0; ni < 4; ++ni) acc2[mi][ni] = vzero;
#pragma unroll
  for (int ks = 0; ks < 8; ++ks) {
    short8 a[4], bv[4];
#pragma unroll
    for (int mi = 0; mi < 4; ++mi)
      a[mi] = *(const short8*)(Wbf + (size_t)(wm0 + mi * 16 + hq) * 256 + ks * 32 + g2 * 8);
#pragma unroll
    for (int ni = 0; ni < 4; ++ni)
      bv[ni] = *(const short8*)(Bs + (ni * 16 + hq) * 264 + ks * 32 + g2 * 8);
#pragma unroll
    for (int mi = 0; mi < 4; ++mi)
#pragma unroll
      for (int ni = 0; ni < 4; ++ni)
        acc2[mi][ni] = __builtin_amdgcn_mfma_f32_16x16x32_bf16(a[mi], bv[ni], acc2[mi][ni], 0, 0, 0);
  }

#pragma unroll
  for (int mi = 0; mi < 4; ++mi) {
#pragma unroll
    for (int r = 0; r < 4; ++r) {
      int o = wm0 + mi * 16 + g2 * 4 + r;
      float bias = conv_b[o];
      float* op = outp + ((size_t)(b * 256 + o)) * HW + hw0;
#pragma unroll
      for (int ni = 0; ni < 4; ++ni) op[ni * 16 + hq] = acc2[mi][ni][r] + bias;
    }
  }
}

extern "C" void kernel_launch(void* const* d_in, const int* in_sizes, int n_in,
                              void* d_out, int out_size, void* d_ws, size_t ws_size,
                              hipStream_t stream) {
  const float* x      = (const float*)d_in[0];
  const float* conv_w = (const float*)d_in[1];
  const float* conv_b = (const float*)d_in[2];
  const float* fc1_w  = (const float*)d_in[3];
  const float* fc1_b  = (const float*)d_in[4];
  const float* fc2_w  = (const float*)d_in[5];
  const float* fc2_b  = (const float*)d_in[6];
  const float* w5     = (const float*)d_in[7];
  const float* b5     = (const float*)d_in[8];
  const float* w1x7   = (const float*)d_in[9];
  const float* b1x7   = (const float*)d_in[10];
  const float* w7x1   = (const float*)d_in[11];
  const float* b7x1   = (const float*)d_in[12];
  const float* w1x11  = (const float*)d_in[13];
  const float* b1x11  = (const float*)d_in[14];
  const float* w11x1  = (const float*)d_in[15];
  const float* b11x1  = (const float*)d_in[16];
  const float* w1x21  = (const float*)d_in[17];
  const float* b1x21  = (const float*)d_in[18];
  const float* w21x1  = (const float*)d_in[19];
  const float* b21x1  = (const float*)d_in[20];
  float* out = (float*)d_out;

  char* ws = (char*)d_ws;
  unsigned short* Wbf = (unsigned short*)(ws);            // 131072 B
  float* psum   = (float*)(ws + 131072);                  // 16384 B
  unsigned* pme = (unsigned*)(ws + 147456);               // 16384 B
  float* attb   = (float*)(ws + 163840);                  // 16384 B
  float* xbuf   = (float*)(ws + 180224);                  // 51380224 B (xs)

  k0_init<<<256, 256, 0, stream>>>(conv_w, Wbf, psum, pme);
  k1_conv_gelu_pool<<<784, 256, 0, stream>>>(x, Wbf, conv_b, out, psum, pme);
  k2_att<<<16, 256, 0, stream>>>(psum, pme, fc1_w, fc1_b, fc2_w, fc2_b, attb);
  k34_dw<<<4096, 256, 0, stream>>>(out, attb, w5, b5, w1x7, b1x7, w7x1, b7x1,
                                   w1x11, b1x11, w11x1, b11x1, w1x21, b1x21,
                                   w21x1, b21x1, xbuf);
  k5_final<<<784, 256, 0, stream>>>(xbuf, Wbf, conv_b, attb, out, out);
}

// Round 4
// 223.954 us; speedup vs baseline: 1.2376x; 1.1486x over previous
//
#include <hip/hip_runtime.h>
#include <hip/hip_bf16.h>

#define HW 3136
#define NB 16

typedef float f32x4 __attribute__((ext_vector_type(4)));
typedef short short8 __attribute__((ext_vector_type(8)));

__device__ inline unsigned short bfb(float f) {
  union { __hip_bfloat16 h; unsigned short u; } cv;
  cv.h = __float2bfloat16(f);
  return cv.u;
}
__device__ inline unsigned pack2(float lo, float hi) {
  return (unsigned)bfb(lo) | ((unsigned)bfb(hi) << 16);
}
// order-preserving float<->uint encode for atomicMax
__device__ inline unsigned fenc(float f) {
  unsigned u = __float_as_uint(f);
  return (u & 0x80000000u) ? ~u : (u | 0x80000000u);
}
__device__ inline float fdec(unsigned e) {
  return (e & 0x80000000u) ? __uint_as_float(e & 0x7FFFFFFFu) : __uint_as_float(~e);
}
__device__ inline float bf2f(unsigned short u) {
  return __uint_as_float((unsigned)u << 16);
}

// ---------------- K0: convert W to bf16, zero pool buffers ----------------
__global__ __launch_bounds__(256) void k0_init(const float* __restrict__ conv_w,
                                               unsigned short* __restrict__ Wbf,
                                               float* __restrict__ psum,
                                               unsigned* __restrict__ pmaxe) {
  int i = blockIdx.x * 256 + threadIdx.x;
  Wbf[i] = bfb(conv_w[i]);
  if (i < 4096) psum[i] = 0.f;
  else if (i < 8192) pmaxe[i - 4096] = 0u;
}

// ---------------- K1: conv1x1 + bias + GELU -> h ; fused channel pooling ----------------
__global__ __launch_bounds__(256) void k1_conv_gelu_pool(
    const float* __restrict__ x, const unsigned short* __restrict__ Wbf,
    const float* __restrict__ conv_b, float* __restrict__ h_out,
    float* __restrict__ psum, unsigned* __restrict__ pmaxe)
{
  __shared__ __align__(16) unsigned short Bs[64 * 264];
  const int bid = blockIdx.x;
  const int b = bid / 49, tile = bid - 49 * (bid / 49);
  const int hw0 = tile * 64;
  const int t = threadIdx.x;

  {
    int g = t & 127, half = t >> 7;
    const float* p0 = x + ((size_t)(b * 256 + 2 * g)) * HW + hw0 + half * 32;
    const float* p1 = p0 + HW;
    unsigned* Bd = (unsigned*)Bs;
#pragma unroll
    for (int i = 0; i < 32; i += 4) {
      float4 a4 = *(const float4*)(p0 + i);
      float4 c4 = *(const float4*)(p1 + i);
      int hw = half * 32 + i;
      Bd[(hw + 0) * 132 + g] = pack2(a4.x, c4.x);
      Bd[(hw + 1) * 132 + g] = pack2(a4.y, c4.y);
      Bd[(hw + 2) * 132 + g] = pack2(a4.z, c4.z);
      Bd[(hw + 3) * 132 + g] = pack2(a4.w, c4.w);
    }
  }
  __syncthreads();

  const int w = t >> 6, l = t & 63, hq = l & 15, g2 = l >> 4;
  const int wm0 = w * 64;
  const f32x4 vzero = {0.f, 0.f, 0.f, 0.f};
  f32x4 acc[4][4];
#pragma unroll
  for (int mi = 0; mi < 4; ++mi)
#pragma unroll
    for (int ni = 0; ni < 4; ++ni) acc[mi][ni] = vzero;

#pragma unroll
  for (int ks = 0; ks < 8; ++ks) {
    short8 a[4], bv[4];
#pragma unroll
    for (int mi = 0; mi < 4; ++mi)
      a[mi] = *(const short8*)(Wbf + (size_t)(wm0 + mi * 16 + hq) * 256 + ks * 32 + g2 * 8);
#pragma unroll
    for (int ni = 0; ni < 4; ++ni)
      bv[ni] = *(const short8*)(Bs + (ni * 16 + hq) * 264 + ks * 32 + g2 * 8);
#pragma unroll
    for (int mi = 0; mi < 4; ++mi)
#pragma unroll
      for (int ni = 0; ni < 4; ++ni)
        acc[mi][ni] = __builtin_amdgcn_mfma_f32_16x16x32_bf16(a[mi], bv[ni], acc[mi][ni], 0, 0, 0);
  }

#pragma unroll
  for (int mi = 0; mi < 4; ++mi) {
#pragma unroll
    for (int r = 0; r < 4; ++r) {
      int o = wm0 + mi * 16 + g2 * 4 + r;
      float bias = conv_b[o];
      float v[4];
#pragma unroll
      for (int ni = 0; ni < 4; ++ni) {
        float s = acc[mi][ni][r] + bias;
        v[ni] = 0.5f * s * (1.0f + erff(s * 0.70710678118654752f));
      }
      float* hp = h_out + ((size_t)(b * 256 + o)) * HW + hw0;
      hp[0 * 16 + hq] = v[0];
      hp[1 * 16 + hq] = v[1];
      hp[2 * 16 + hq] = v[2];
      hp[3 * 16 + hq] = v[3];
      float sm = v[0] + v[1] + v[2] + v[3];
      float mx = fmaxf(fmaxf(v[0], v[1]), fmaxf(v[2], v[3]));
#pragma unroll
      for (int d = 1; d < 16; d <<= 1) {
        sm += __shfl_xor(sm, d);
        mx = fmaxf(mx, __shfl_xor(mx, d));
      }
      if (hq == 0) {
        atomicAdd(psum + b * 256 + o, sm);
        atomicMax(pmaxe + b * 256 + o, fenc(mx));
      }
    }
  }
}

// ---------------- K2: channel attention FCs ----------------
__global__ __launch_bounds__(256) void k2_att(
    const float* __restrict__ psum, const unsigned* __restrict__ pmaxe,
    const float* __restrict__ fc1_w, const float* __restrict__ fc1_b,
    const float* __restrict__ fc2_w, const float* __restrict__ fc2_b,
    float* __restrict__ att)
{
  int b = blockIdx.x, t = threadIdx.x;
  __shared__ float hA[64], hM[64];
  if (t < 128) {
    int j = t & 63;
    bool ism = t >= 64;
    float s = fc1_b[j];
    for (int c = 0; c < 256; ++c) {
      float p = ism ? fdec(pmaxe[b * 256 + c]) : (psum[b * 256 + c] * (1.f / 3136.f));
      s += p * fc1_w[j * 256 + c];
    }
    s = fmaxf(s, 0.f);
    if (ism) hM[j] = s; else hA[j] = s;
  }
  __syncthreads();
  float s1 = fc2_b[t], s2 = s1;
  for (int j = 0; j < 64; ++j) {
    float wv = fc2_w[t * 64 + j];
    s1 += hA[j] * wv;
    s2 += hM[j] * wv;
  }
  att[b * 256 + t] = 1.f / (1.f + expf(-s1)) + 1.f / (1.f + expf(-s2));
}

// ---------------- K34 v3: fused depthwise chain, one plane per block ----------------
// LDS (~40.3KB -> 4 blocks/CU):
//   B0 fp32 [4256]: P0 halo h [60][60]; after P1 sync rewritten as x_init [56][76] (col+10, pads 0)
//   T1/T2/T3 bf16 row-major [62|66|76][56], vertical pad rows zeroed once
// Tasks: P1/P2/PB: 392 col tasks (8 rows x 1 col); PA: 392 row tasks (1 row x 8 cols)
// x_init lives in registers xv0/xv1 between P1 and PB (same task mapping).
__global__ __launch_bounds__(256) void k34_dw(
    const float* __restrict__ h_in, const float* __restrict__ att,
    const float* __restrict__ w5, const float* __restrict__ b5,
    const float* __restrict__ w1x7, const float* __restrict__ b1x7,
    const float* __restrict__ w7x1, const float* __restrict__ b7x1,
    const float* __restrict__ w1x11, const float* __restrict__ b1x11,
    const float* __restrict__ w11x1, const float* __restrict__ b11x1,
    const float* __restrict__ w1x21, const float* __restrict__ b1x21,
    const float* __restrict__ w21x1, const float* __restrict__ b21x1,
    float* __restrict__ xs_out)
{
  __shared__ __align__(16) float B0[4256];
  __shared__ __align__(16) unsigned short T1[62 * 56];  // r = y+3
  __shared__ __align__(16) unsigned short T2[66 * 56];  // r = y+5
  __shared__ __align__(16) unsigned short T3[76 * 56];  // r = y+10
  __shared__ __align__(16) float wk5a[25];
  __shared__ __align__(16) float wk[78]; // [0,7)w1x7 [7,14)w7x1 [14,25)w1x11 [25,36)w11x1 [36,57)w1x21 [57,78)w21x1

  const int bid = blockIdx.x;
  const int b = bid >> 8, c = bid & 255;
  const int t = threadIdx.x;
  const size_t plane = (size_t)(b * 256 + c) * HW;
  const float a = att[b * 256 + c];

  if (t < 25) wk5a[t] = w5[c * 25 + t] * a;   // fold channel attention into dw5x5 weights
  if (t >= 32 && t < 110) {
    int k = t - 32;
    float v;
    if (k < 7) v = w1x7[c * 7 + k];
    else if (k < 14) v = w7x1[c * 7 + k - 7];
    else if (k < 25) v = w1x11[c * 11 + k - 14];
    else if (k < 36) v = w11x1[c * 11 + k - 25];
    else if (k < 57) v = w1x21[c * 21 + k - 36];
    else v = w21x1[c * 21 + k - 57];
    wk[k] = v;
  }
  { // zero vertical pad rows of T1/T2/T3 (once; PA never writes them)
    unsigned* T1d = (unsigned*)T1; unsigned* T2d = (unsigned*)T2; unsigned* T3d = (unsigned*)T3;
    for (int i = t; i < 1008; i += 256) {
      if (i < 84) T1d[i] = 0;                       // rows 0..2
      else if (i < 168) T1d[1652 + i - 84] = 0;     // rows 59..61
      else if (i < 308) T2d[i - 168] = 0;           // rows 0..4
      else if (i < 448) T2d[1708 + i - 308] = 0;    // rows 61..65
      else if (i < 728) T3d[i - 448] = 0;           // rows 0..9
      else T3d[1848 + i - 728] = 0;                 // rows 66..75
    }
  }
  { // P0: stage halo'd raw h (rows/cols -2..57) into B0h[60][60]
    const float* hp = h_in + plane;
    for (int tau = t; tau < 960; tau += 256) {
      int ly = tau >> 4, g = tau & 15;
      int gy = ly - 2, gxb = 4 * g - 4;
      bool rowok = (unsigned)gy < 56u;
#pragma unroll
      for (int e = 0; e < 4; ++e) {
        int gx = gxb + e, col = gx + 2;
        if ((unsigned)col < 60u) {
          float v = 0.f;
          if (rowok && (unsigned)gx < 56u) v = hp[gy * 56 + gx];
          B0[ly * 60 + col] = v;
        }
      }
    }
  }
  __syncthreads();

  // P1: dw5x5 -> registers. 392 tasks, 2 static rounds.
  float xv0[8], xv1[8];
  const float bias5 = b5[c];
  {
    int tau = t, yq = tau / 56, xx = tau - yq * 56, y0 = yq * 8;
    float accv[8];
#pragma unroll
    for (int d = 0; d < 8; ++d) accv[d] = bias5;
#pragma unroll
    for (int kx = 0; kx < 5; ++kx) {
      float col[12];
#pragma unroll
      for (int ry = 0; ry < 12; ++ry) col[ry] = B0[(y0 + ry) * 60 + xx + kx];
#pragma unroll
      for (int ky = 0; ky < 5; ++ky) {
        float wv = wk5a[ky * 5 + kx];
#pragma unroll
        for (int d = 0; d < 8; ++d) accv[d] += col[d + ky] * wv;
      }
    }
#pragma unroll
    for (int d = 0; d < 8; ++d) xv0[d] = accv[d];
  }
  if (t < 136) {
    int tau = t + 256, yq = tau / 56, xx = tau - yq * 56, y0 = yq * 8;
    float accv[8];
#pragma unroll
    for (int d = 0; d < 8; ++d) accv[d] = bias5;
#pragma unroll
    for (int kx = 0; kx < 5; ++kx) {
      float col[12];
#pragma unroll
      for (int ry = 0; ry < 12; ++ry) col[ry] = B0[(y0 + ry) * 60 + xx + kx];
#pragma unroll
      for (int ky = 0; ky < 5; ++ky) {
        float wv = wk5a[ky * 5 + kx];
#pragma unroll
        for (int d = 0; d < 8; ++d) accv[d] += col[d + ky] * wv;
      }
    }
#pragma unroll
    for (int d = 0; d < 8; ++d) xv1[d] = accv[d];
  }
  __syncthreads();

  // P2: rewrite B0 as padded x_init [56][76] (data at col+10), zero col pads
  {
    int tau = t, yq = tau / 56, xx = tau - yq * 56, y0 = yq * 8;
#pragma unroll
    for (int d = 0; d < 8; ++d) B0[(y0 + d) * 76 + 10 + xx] = xv0[d];
  }
  if (t < 136) {
    int tau = t + 256, yq = tau / 56, xx = tau - yq * 56, y0 = yq * 8;
#pragma unroll
    for (int d = 0; d < 8; ++d) B0[(y0 + d) * 76 + 10 + xx] = xv1[d];
  }
  for (int i = t; i < 1120; i += 256) {
    int y = i / 20, j = i - y * 20;
    int lx = (j < 10) ? j : (56 + j);   // pads: cols 0..9 and 66..75 (data at 10..65)
    B0[y * 76 + lx] = 0.f;
  }
  __syncthreads();

  // PA: fused horizontal convs. Task = (row y, 8 cols x0..x0+7). win read ONCE.
  const float bb1 = b1x7[c], bb2 = b1x11[c], bb3 = b1x21[c];
  {
#pragma unroll
    for (int rnd = 0; rnd < 2; ++rnd) {
      int tau = t + rnd * 256;
      if (rnd == 1 && t >= 136) break;
      int y = tau / 7, x0 = (tau - y * 7) * 8;
      float win[28];
      const float* rp = B0 + y * 76 + x0;
#pragma unroll
      for (int j = 0; j < 28; j += 4) {
        float4 q = *(const float4*)(rp + j);
        win[j] = q.x; win[j + 1] = q.y; win[j + 2] = q.z; win[j + 3] = q.w;
      }
      float o1[8], o2[8], o3[8];
#pragma unroll
      for (int d = 0; d < 8; ++d) { o1[d] = bb1; o2[d] = bb2; o3[d] = bb3; }
#pragma unroll
      for (int k = 0; k < 7; ++k) {
        float wv = wk[k];
#pragma unroll
        for (int d = 0; d < 8; ++d) o1[d] += win[d + k + 7] * wv;
      }
#pragma unroll
      for (int k = 0; k < 11; ++k) {
        float wv = wk[14 + k];
#pragma unroll
        for (int d = 0; d < 8; ++d) o2[d] += win[d + k + 5] * wv;
      }
#pragma unroll
      for (int k = 0; k < 21; ++k) {
        float wv = wk[36 + k];
#pragma unroll
        for (int d = 0; d < 8; ++d) o3[d] += win[d + k] * wv;
      }
      uint4 s1, s2, s3;
      s1.x = pack2(o1[0], o1[1]); s1.y = pack2(o1[2], o1[3]); s1.z = pack2(o1[4], o1[5]); s1.w = pack2(o1[6], o1[7]);
      s2.x = pack2(o2[0], o2[1]); s2.y = pack2(o2[2], o2[3]); s2.z = pack2(o2[4], o2[5]); s2.w = pack2(o2[6], o2[7]);
      s3.x = pack2(o3[0], o3[1]); s3.y = pack2(o3[2], o3[3]); s3.z = pack2(o3[4], o3[5]); s3.w = pack2(o3[6], o3[7]);
      *(uint4*)&T1[(y + 3) * 56 + x0] = s1;
      *(uint4*)&T2[(y + 5) * 56 + x0] = s2;
      *(uint4*)&T3[(y + 10) * 56 + x0] = s3;
    }
  }
  __syncthreads();

  // PB: fused vertical convs + x_init add (registers) -> global store
  const float vb = b7x1[c] + b11x1[c] + b21x1[c];
  float* op = xs_out + plane;
  {
    int tau = t, yq = tau / 56, xx = tau - yq * 56, y0 = yq * 8;
    float r8[8];
#pragma unroll
    for (int d = 0; d < 8; ++d) r8[d] = xv0[d] + vb;
    {
      float cw[14];
#pragma unroll
      for (int j = 0; j < 14; ++j) cw[j] = bf2f(T1[(y0 + j) * 56 + xx]);
#pragma unroll
      for (int k = 0; k < 7; ++k) {
        float wv = wk[7 + k];
#pragma unroll
        for (int d = 0; d < 8; ++d) r8[d] += cw[d + k] * wv;
      }
    }
    {
      float cw[18];
#pragma unroll
      for (int j = 0; j < 18; ++j) cw[j] = bf2f(T2[(y0 + j) * 56 + xx]);
#pragma unroll
      for (int k = 0; k < 11; ++k) {
        float wv = wk[25 + k];
#pragma unroll
        for (int d = 0; d < 8; ++d) r8[d] += cw[d + k] * wv;
      }
    }
    {
      float cw[28];
#pragma unroll
      for (int j = 0; j < 28; ++j) cw[j] = bf2f(T3[(y0 + j) * 56 + xx]);
#pragma unroll
      for (int k = 0; k < 21; ++k) {
        float wv = wk[57 + k];
#pragma unroll
        for (int d = 0; d < 8; ++d) r8[d] += cw[d + k] * wv;
      }
    }
#pragma unroll
    for (int d = 0; d < 8; ++d) op[(y0 + d) * 56 + xx] = r8[d];
  }
  if (t < 136) {
    int tau = t + 256, yq = tau / 56, xx = tau - yq * 56, y0 = yq * 8;
    float r8[8];
#pragma unroll
    for (int d = 0; d < 8; ++d) r8[d] = xv1[d] + vb;
    {
      float cw[14];
#pragma unroll
      for (int j = 0; j < 14; ++j) cw[j] = bf2f(T1[(y0 + j) * 56 + xx]);
#pragma unroll
      for (int k = 0; k < 7; ++k) {
        float wv = wk[7 + k];
#pragma unroll
        for (int d = 0; d < 8; ++d) r8[d] += cw[d + k] * wv;
      }
    }
    {
      float cw[18];
#pragma unroll
      for (int j = 0; j < 18; ++j) cw[j] = bf2f(T2[(y0 + j) * 56 + xx]);
#pragma unroll
      for (int k = 0; k < 11; ++k) {
        float wv = wk[25 + k];
#pragma unroll
        for (int d = 0; d < 8; ++d) r8[d] += cw[d + k] * wv;
      }
    }
    {
      float cw[28];
#pragma unroll
      for (int j = 0; j < 28; ++j) cw[j] = bf2f(T3[(y0 + j) * 56 + xx]);
#pragma unroll
      for (int k = 0; k < 21; ++k) {
        float wv = wk[57 + k];
#pragma unroll
        for (int d = 0; d < 8; ++d) r8[d] += cw[d + k] * wv;
      }
    }
#pragma unroll
    for (int d = 0; d < 8; ++d) op[(y0 + d) * 56 + xx] = r8[d];
  }
}

// ---------------- K5: spatial_att = W*xs+b ; out = sa*(att*h) ; result = W*out+b ----------------
__global__ __launch_bounds__(256) void k5_final(
    const float* __restrict__ xs, const unsigned short* __restrict__ Wbf,
    const float* __restrict__ conv_b, const float* __restrict__ att,
    const float* __restrict__ h_in, float* __restrict__ outp)
{
  __shared__ __align__(16) unsigned short Bs[64 * 264];
  const int bid = blockIdx.x;
  const int b = bid / 49, tile = bid - 49 * (bid / 49);
  const int hw0 = tile * 64;
  const int t = threadIdx.x;

  {
    int g = t & 127, half = t >> 7;
    const float* p0 = xs + ((size_t)(b * 256 + 2 * g)) * HW + hw0 + half * 32;
    const float* p1 = p0 + HW;
    unsigned* Bd = (unsigned*)Bs;
#pragma unroll
    for (int i = 0; i < 32; i += 4) {
      float4 a4 = *(const float4*)(p0 + i);
      float4 c4 = *(const float4*)(p1 + i);
      int hw = half * 32 + i;
      Bd[(hw + 0) * 132 + g] = pack2(a4.x, c4.x);
      Bd[(hw + 1) * 132 + g] = pack2(a4.y, c4.y);
      Bd[(hw + 2) * 132 + g] = pack2(a4.z, c4.z);
      Bd[(hw + 3) * 132 + g] = pack2(a4.w, c4.w);
    }
  }
  __syncthreads();

  const int w = t >> 6, l = t & 63, hq = l & 15, g2 = l >> 4;
  const int wm0 = w * 64;
  const f32x4 vzero = {0.f, 0.f, 0.f, 0.f};
  f32x4 acc[4][4];
#pragma unroll
  for (int mi = 0; mi < 4; ++mi)
#pragma unroll
    for (int ni = 0; ni < 4; ++ni) acc[mi][ni] = vzero;

#pragma unroll
  for (int ks = 0; ks < 8; ++ks) {
    short8 a[4], bv[4];
#pragma unroll
    for (int mi = 0; mi < 4; ++mi)
      a[mi] = *(const short8*)(Wbf + (size_t)(wm0 + mi * 16 + hq) * 256 + ks * 32 + g2 * 8);
#pragma unroll
    for (int ni = 0; ni < 4; ++ni)
      bv[ni] = *(const short8*)(Bs + (ni * 16 + hq) * 264 + ks * 32 + g2 * 8);
#pragma unroll
    for (int mi = 0; mi < 4; ++mi)
#pragma unroll
      for (int ni = 0; ni < 4; ++ni)
        acc[mi][ni] = __builtin_amdgcn_mfma_f32_16x16x32_bf16(a[mi], bv[ni], acc[mi][ni], 0, 0, 0);
  }
  __syncthreads();

#pragma unroll
  for (int mi = 0; mi < 4; ++mi) {
#pragma unroll
    for (int r = 0; r < 4; ++r) {
      int o = wm0 + mi * 16 + g2 * 4 + r;
      float bias = conv_b[o];
      float av = att[b * 256 + o];
      const float* hp = h_in + ((size_t)(b * 256 + o)) * HW + hw0;
#pragma unroll
      for (int ni = 0; ni < 4; ++ni) {
        float sa = acc[mi][ni][r] + bias;
        float ov = sa * (av * hp[ni * 16 + hq]);
        Bs[(ni * 16 + hq) * 264 + o] = bfb(ov);
      }
    }
  }
  __syncthreads();

  f32x4 acc2[4][4];
#pragma unroll
  for (int mi = 0; mi < 4; ++mi)
#pragma unroll
    for (int ni = 0; ni < 4; ++ni) acc2[mi][ni] = vzero;
#pragma unroll
  for (int ks = 0; ks < 8; ++ks) {
    short8 a[4], bv[4];
#pragma unroll
    for (int mi = 0; mi < 4; ++mi)
      a[mi] = *(const short8*)(Wbf + (size_t)(wm0 + mi * 16 + hq) * 256 + ks * 32 + g2 * 8);
#pragma unroll
    for (int ni = 0; ni < 4; ++ni)
      bv[ni] = *(const short8*)(Bs + (ni * 16 + hq) * 264 + ks * 32 + g2 * 8);
#pragma unroll
    for (int mi = 0; mi < 4; ++mi)
#pragma unroll
      for (int ni = 0; ni < 4; ++ni)
        acc2[mi][ni] = __builtin_amdgcn_mfma_f32_16x16x32_bf16(a[mi], bv[ni], acc2[mi][ni], 0, 0, 0);
  }

#pragma unroll
  for (int mi = 0; mi < 4; ++mi) {
#pragma unroll
    for (int r = 0; r < 4; ++r) {
      int o = wm0 + mi * 16 + g2 * 4 + r;
      float bias = conv_b[o];
      float* op = outp + ((size_t)(b * 256 + o)) * HW + hw0;
#pragma unroll
      for (int ni = 0; ni < 4; ++ni) op[ni * 16 + hq] = acc2[mi][ni][r] + bias;
    }
  }
}

extern "C" void kernel_launch(void* const* d_in, const int* in_sizes, int n_in,
                              void* d_out, int out_size, void* d_ws, size_t ws_size,
                              hipStream_t stream) {
  const float* x      = (const float*)d_in[0];
  const float* conv_w = (const float*)d_in[1];
  const float* conv_b = (const float*)d_in[2];
  const float* fc1_w  = (const float*)d_in[3];
  const float* fc1_b  = (const float*)d_in[4];
  const float* fc2_w  = (const float*)d_in[5];
  const float* fc2_b  = (const float*)d_in[6];
  const float* w5     = (const float*)d_in[7];
  const float* b5     = (const float*)d_in[8];
  const float* w1x7   = (const float*)d_in[9];
  const float* b1x7   = (const float*)d_in[10];
  const float* w7x1   = (const float*)d_in[11];
  const float* b7x1   = (const float*)d_in[12];
  const float* w1x11  = (const float*)d_in[13];
  const float* b1x11  = (const float*)d_in[14];
  const float* w11x1  = (const float*)d_in[15];
  const float* b11x1  = (const float*)d_in[16];
  const float* w1x21  = (const float*)d_in[17];
  const float* b1x21  = (const float*)d_in[18];
  const float* w21x1  = (const float*)d_in[19];
  const float* b21x1  = (const float*)d_in[20];
  float* out = (float*)d_out;

  char* ws = (char*)d_ws;
  unsigned short* Wbf = (unsigned short*)(ws);            // 131072 B
  float* psum   = (float*)(ws + 131072);                  // 16384 B
  unsigned* pme = (unsigned*)(ws + 147456);               // 16384 B
  float* attb   = (float*)(ws + 163840);                  // 16384 B
  float* xbuf   = (float*)(ws + 180224);                  // 51380224 B (xs)

  k0_init<<<256, 256, 0, stream>>>(conv_w, Wbf, psum, pme);
  k1_conv_gelu_pool<<<784, 256, 0, stream>>>(x, Wbf, conv_b, out, psum, pme);
  k2_att<<<16, 256, 0, stream>>>(psum, pme, fc1_w, fc1_b, fc2_w, fc2_b, attb);
  k34_dw<<<4096, 256, 0, stream>>>(out, attb, w5, b5, w1x7, b1x7, w7x1, b7x1,
                                   w1x11, b1x11, w11x1, b11x1, w1x21, b1x21,
                                   w21x1, b21x1, xbuf);
  k5_final<<<784, 256, 0, stream>>>(xbuf, Wbf, conv_b, attb, out, out);
}